// Round 13
// baseline (213.232 us; speedup 1.0000x reference)
//
#include <hip/hip_runtime.h>
#include <hip/hip_bf16.h>
#include <hip/hip_fp16.h>
#include <math.h>

#define LQ_  2048
#define LK_  2048
#define D_   128
#define B_   16
#define LN_EPS 1e-5f
#define TK_  32
#define NTILE (LK_ / TK_)

// Pre-converted tile images in workspace (round-8 layouts):
#define KH_TILE_US 4096          // 32 rows x 128 d fp16 swizzled (8192 B)
#define VT_TILE_U  2048          // 128 d x 16 slot uint, PV-permuted (8192 B)
#define KH_BYTES   ((size_t)B_ * NTILE * KH_TILE_US * 2)   // 8,388,608
#define VT_OFF     KH_BYTES                                 // 8,388,608
// total ws: 16,777,216 B

typedef __attribute__((ext_vector_type(8))) short short8;
typedef __attribute__((ext_vector_type(8))) _Float16 half8;
typedef __attribute__((ext_vector_type(4))) float f32x4;

union FragU { uint4 u4; short8 s8; half8 h8; unsigned int u[4]; };

__device__ __forceinline__ unsigned int pk_bf16(float a, float b) {
  __hip_bfloat162 h = __float22bfloat162_rn(make_float2(a, b));
  unsigned int u;
  __builtin_memcpy(&u, &h, 4);
  return u;
}
__device__ __forceinline__ unsigned int pk_f16(float a, float b) {
  __half2 h = __floats2half2_rn(a, b);
  unsigned int u;
  __builtin_memcpy(&u, &h, 4);
  return u;
}
__device__ __forceinline__ float f16_lo(unsigned int u) {
  unsigned short s = (unsigned short)(u & 0xffffu);
  __half h; __builtin_memcpy(&h, &s, 2); return __half2float(h);
}
__device__ __forceinline__ float f16_hi(unsigned int u) {
  unsigned short s = (unsigned short)(u >> 16);
  __half h; __builtin_memcpy(&h, &s, 2); return __half2float(h);
}

// K tiles: ushort [32 rows][128 d], 16B(8-elem)-chunk XOR swizzle by row.
__device__ __forceinline__ int idxK(int row, int d) {
  return row * 128 + ((((d >> 3) ^ row) & 15) << 3) + (d & 7);
}
// Vt: uint [128 d][16 slots]; 16B chunk rotation p = (g + (d>>1)) & 3.
// Slot->kp mapping is the PV-permuted order (see conv_kv emit).
__device__ __forceinline__ int idxVt(int d, int slot) {
  return d * 16 + ((((slot >> 2) + (d >> 1)) & 3) << 2) + (slot & 3);
}

// Barrier that drains this wave's tile-stage DMA (stage ops are the oldest;
// the 4 newest vm ops -- prefetched mask float4 loads -- stay in flight).
__device__ __forceinline__ void barrier_stage() {
  asm volatile("s_waitcnt vmcnt(4) lgkmcnt(0)\n\ts_barrier" ::: "memory");
}

__device__ __forceinline__ void gld_lds16(const void* g, void* l) {
  __builtin_amdgcn_global_load_lds((const __attribute__((address_space(1))) void*)g,
                                   (__attribute__((address_space(3))) void*)l, 16, 0, 0);
}

// ---------------- pre-pass: K -> fp16 swizzled, V -> bf16-pair Vt ----------
__global__ __launch_bounds__(256) void conv_kv(
    const float* __restrict__ kg, const float* __restrict__ vg,
    unsigned short* __restrict__ khg, unsigned int* __restrict__ vtg)
{
  __shared__ float Vlt[128 * 33];   // V tile transposed, +1-pad rows
  const int tid = threadIdx.x;
  const int blk = blockIdx.x;          // b*64 + t
  const int b = blk >> 6;
  const int t = blk & 63;

  const float* ks = kg + ((size_t)b * LK_ + t * 32) * D_;
  const float* vs = vg + ((size_t)b * LK_ + t * 32) * D_;
  unsigned short* kh = khg + (size_t)blk * KH_TILE_US;
  unsigned int*   vt = vtg + (size_t)blk * VT_TILE_U;

  // K: 512 (row, 8-chunk) items; coalesced reads, 16B swizzled writes.
#pragma unroll
  for (int it = 0; it < 2; it++) {
    const int item = tid + it * 256;
    const int row = item >> 4;
    const int c8  = item & 15;
    const float* p = ks + row * D_ + c8 * 8;
    float4 x = *(const float4*)(p);
    float4 y = *(const float4*)(p + 4);
    FragU H;
    H.u[0] = pk_f16(x.x, x.y); H.u[1] = pk_f16(x.z, x.w);
    H.u[2] = pk_f16(y.x, y.y); H.u[3] = pk_f16(y.z, y.w);
    *(uint4*)&kh[idxK(row, c8 * 8)] = H.u4;
  }

  // V tile -> LDS transposed (coalesced global reads).
#pragma unroll
  for (int i = 0; i < 4; i++) {
    const int item = tid + i * 256;
    const int r = item >> 5, c4 = item & 31;
    float4 x = *(const float4*)&vs[r * D_ + c4 * 4];
    Vlt[(c4 * 4 + 0) * 33 + r] = x.x;
    Vlt[(c4 * 4 + 1) * 33 + r] = x.y;
    Vlt[(c4 * 4 + 2) * 33 + r] = x.z;
    Vlt[(c4 * 4 + 3) * 33 + r] = x.w;
  }
  __syncthreads();

  // Emit Vt image linearly (coalesced writes); inverse-map phys slot -> kp.
#pragma unroll
  for (int i = 0; i < 8; i++) {
    const int o = tid + i * 256;
    const int d = o >> 4, sp = o & 15;
    const int gl = ((sp >> 2) - (d >> 1)) & 3;
    const int c  = sp & 3;
    const int kp = 2 * gl + ((c >> 1) << 3) + (c & 1);
    vt[o] = pk_bf16(Vlt[d * 33 + 2 * kp], Vlt[d * 33 + 2 * kp + 1]);
  }
}

// ---------------- main fused attention + LN ----------------
// Stage one tile's images into LDS via global_load_lds: 4 x 1KiB per wave,
// 4 cooperating waves cover 8 KB K + 8 KB Vt.
__device__ __forceinline__ void stage_tile(int w, int lane,
    const unsigned short* khT, const unsigned int* vtT,
    int tile, char* khs, char* vts)
{
  const char* gkh = (const char*)(khT + (size_t)tile * KH_TILE_US);
  const char* gvt = (const char*)(vtT + (size_t)tile * VT_TILE_U);
#pragma unroll
  for (int c = 0; c < 2; c++) {
    const int off = (w + 4 * c) << 10;            // 1 KiB chunks
    gld_lds16(gkh + off + lane * 16, khs + off);
    gld_lds16(gvt + off + lane * 16, vts + off);
  }
}

// Each wave owns 32 q-rows (2 groups of 16). K/Bv fragments read ONCE per
// wave serve both groups -> per-row LDS reads halved vs round 8.
__global__ __launch_bounds__(256, 1) void attn_ln_mfma(
    const float* __restrict__ qg, const float* __restrict__ maskg,
    const float* __restrict__ gammag, const float* __restrict__ betag,
    const unsigned short* __restrict__ khg, const unsigned int* __restrict__ vtg,
    float* __restrict__ outg)
{
  __shared__ unsigned short KhS[2][32 * 128];   // 16 KB (fp16)
  __shared__ unsigned int   VtW[2][128 * 16];   // 16 KB
  // total 32,768 B; block covers 128 q-rows -> grid 256, 1 block/CU.

  const int tid  = threadIdx.x;
  const int w    = tid >> 6;     // wave owns q-rows [q0 + w*32, +32)
  const int lane = tid & 63;
  const int quad = lane >> 4;
  const int lr   = lane & 15;

  // XCD swizzle: 32 slots per XCD = 2 batches x 16 q-slots of 128 rows.
  const int id   = blockIdx.x;   // 0..255
  const int xcd  = id & 7;
  const int slot = id >> 3;      // 0..31
  const int b    = xcd * 2 + (slot >> 4);
  const int q0   = (slot & 15) * 128;

  const unsigned short* khT = khg + (size_t)b * NTILE * KH_TILE_US;
  const unsigned int*   vtT = vtg + (size_t)b * NTILE * VT_TILE_U;

  // mask rows for this lane's two q-rows (swapped layout: row = lr).
  const float* mrow0 = maskg + (size_t)(q0 + w * 32 + lr) * LK_ + quad * 4;
  const float* mrow1 = mrow0 + (size_t)16 * LK_;

  // ---- issue tile-0 stage DMA + mask(0) prefetch (fly during Q build) ----
  stage_tile(w, lane, khT, vtT, 0, (char*)&KhS[0][0], (char*)&VtW[0][0]);
  float4 mA[2][2], mB[2][2];
  mA[0][0] = *(const float4*)(mrow0);
  mA[0][1] = *(const float4*)(mrow0 + 16);
  mA[1][0] = *(const float4*)(mrow1);
  mA[1][1] = *(const float4*)(mrow1 + 16);

  // ---- Q fragments (fp16 hi/lo) for both 16-row groups ----
  half8 qh[2][4], ql[2][4];
#pragma unroll
  for (int g = 0; g < 2; g++) {
    const float* qrow = qg + ((size_t)b * LQ_ + q0 + w * 32 + g * 16 + lr) * D_ + quad * 8;
#pragma unroll
    for (int c = 0; c < 4; c++) {
      float4 x = *(const float4*)(qrow + c * 32);
      float4 y = *(const float4*)(qrow + c * 32 + 4);
      FragU H, L;
      H.u[0] = pk_f16(x.x, x.y); H.u[1] = pk_f16(x.z, x.w);
      H.u[2] = pk_f16(y.x, y.y); H.u[3] = pk_f16(y.z, y.w);
      L.u[0] = pk_f16(x.x - f16_lo(H.u[0]), x.y - f16_hi(H.u[0]));
      L.u[1] = pk_f16(x.z - f16_lo(H.u[1]), x.w - f16_hi(H.u[1]));
      L.u[2] = pk_f16(y.x - f16_lo(H.u[2]), y.y - f16_hi(H.u[2]));
      L.u[3] = pk_f16(y.z - f16_lo(H.u[3]), y.w - f16_hi(H.u[3]));
      qh[g][c] = H.h8; ql[g][c] = L.h8;
    }
  }

  float l_part[2] = {0.f, 0.f};  // per group: sum of p, row = lr
  f32x4 o[2][8];                 // [g][nb]: q-row = g*16+quad*4+reg, d = nb*16+lr
  const f32x4 zf = {0.f, 0.f, 0.f, 0.f};
#pragma unroll
  for (int g = 0; g < 2; g++)
#pragma unroll
    for (int n = 0; n < 8; n++) o[g][n] = zf;

  // One tile body. cur is a literal (0/1); mu holds mask(kt); mask(kt+1) is
  // prefetched into mp (named registers, no copies -> counted vmcnt at use).
  auto body = [&](int kt, int cur, float4 (&mu)[2][2], float4 (&mp)[2][2])
      __attribute__((always_inline)) -> void {
    const unsigned short* khc = &KhS[cur][0];
    const unsigned int*   vtc = &VtW[cur][0];

    // All waves past previous tile's LDS reads; this wave's stage(kt) done.
    // The 4 newest vm ops (mask(kt) float4 loads) stay in flight.
    barrier_stage();

    // ---- issue NEXT tile stage (4 vm) + NEXT mask prefetch (4 vm) ----
    if (kt + 1 < NTILE) {
      stage_tile(w, lane, khT, vtT, kt + 1,
                 (char*)&KhS[cur ^ 1][0], (char*)&VtW[cur ^ 1][0]);
      mp[0][0] = *(const float4*)(mrow0 + (kt + 1) * TK_);
      mp[0][1] = *(const float4*)(mrow0 + (kt + 1) * TK_ + 16);
      mp[1][0] = *(const float4*)(mrow1 + (kt + 1) * TK_);
      mp[1][1] = *(const float4*)(mrow1 + (kt + 1) * TK_ + 16);
    }

    // ---- S^T = K Q^T (fp16 2-term, swapped operands: A=K, B=Q) ----
    // Each K fragment read once, feeds 4 MFMAs (2 groups x hi/lo).
    // sacc[g][ct] lane layout: k = ct*16 + quad*4 + reg, q-row = lr.
    f32x4 sH[2][2], sL[2][2];
#pragma unroll
    for (int g = 0; g < 2; g++) {
      sH[g][0] = zf; sH[g][1] = zf; sL[g][0] = zf; sL[g][1] = zf;
    }
#pragma unroll
    for (int c = 0; c < 4; c++)
#pragma unroll
      for (int ct = 0; ct < 2; ct++) {
        FragU kh;
        kh.u4 = *(const uint4*)&khc[idxK(ct * 16 + lr, c * 32 + quad * 8)];
#pragma unroll
        for (int g = 0; g < 2; g++) {
          sH[g][ct] = __builtin_amdgcn_mfma_f32_16x16x32_f16(kh.h8, qh[g][c], sH[g][ct], 0, 0, 0);
          sL[g][ct] = __builtin_amdgcn_mfma_f32_16x16x32_f16(kh.h8, ql[g][c], sL[g][ct], 0, 0, 0);
        }
      }

    // ---- Bv reads ONCE (serve both groups); overlap the exp chains ----
    FragU Bv[8];
#pragma unroll
    for (int nb = 0; nb < 8; nb++)
      Bv[nb].u4 = *(const uint4*)&vtc[idxVt(nb * 16 + lr, quad * 4)];

    // ---- per-group: max-free softmax in registers, pack, PV ----
#pragma unroll
    for (int g = 0; g < 2; g++) {
      float pv[2][4];
#pragma unroll
      for (int ct = 0; ct < 2; ct++) {
        const float* mf = (const float*)&mu[g][ct];
#pragma unroll
        for (int reg = 0; reg < 4; reg++) {
          float p = __expf(sH[g][ct][reg] + sL[g][ct][reg] + mf[reg]);
          l_part[g] += p;
          pv[ct][reg] = p;
        }
      }
      FragU A;
      A.u[0] = pk_bf16(pv[0][0], pv[0][1]);
      A.u[1] = pk_bf16(pv[0][2], pv[0][3]);
      A.u[2] = pk_bf16(pv[1][0], pv[1][1]);
      A.u[3] = pk_bf16(pv[1][2], pv[1][3]);
#pragma unroll
      for (int nb = 0; nb < 8; nb++)
        o[g][nb] = __builtin_amdgcn_mfma_f32_16x16x32_bf16(A.s8, Bv[nb].s8, o[g][nb], 0, 0, 0);
    }
  };

  for (int kt = 0; kt < NTILE; kt += 2) {
    body(kt,     0, mA, mB);   // consumes mask in mA, prefetches into mB
    body(kt + 1, 1, mB, mA);   // consumes mask in mB, prefetches into mA
  }

  // ---- epilogue: fully wave-internal (round-8 form, per group) ----
  float gam[8], bet[8];
#pragma unroll
  for (int nb = 0; nb < 8; nb++) {
    gam[nb] = gammag[nb * 16 + lr];
    bet[nb] = betag[nb * 16 + lr];
  }

#pragma unroll
  for (int g = 0; g < 2; g++) {
    float lt = l_part[g];
    lt += __shfl_xor(lt, 16, 64);
    lt += __shfl_xor(lt, 32, 64);
    const float invl = 1.f / lt;         // valid at every lane for row = lr

    float inv_l[4];
#pragma unroll
    for (int reg = 0; reg < 4; reg++)
      inv_l[reg] = __shfl(invl, quad * 20 + reg, 64);  // lane quad*16 + (quad*4+reg)

#pragma unroll
    for (int reg = 0; reg < 4; reg++) {
      float s1 = 0.f, s2 = 0.f;
#pragma unroll
      for (int nb = 0; nb < 8; nb++) {
        float v = o[g][nb][reg] * inv_l[reg];
        o[g][nb][reg] = v;
        s1 += v; s2 += v * v;
      }
#pragma unroll
      for (int m = 1; m <= 8; m <<= 1) {
        s1 += __shfl_xor(s1, m, 64);
        s2 += __shfl_xor(s2, m, 64);
      }
      const float mean = s1 * (1.f / 128.f);
      const float var  = s2 * (1.f / 128.f) - mean * mean;
      const float rstd = rsqrtf(var + LN_EPS);

      float* op = outg + ((size_t)b * LQ_ + q0 + w * 32 + g * 16 + quad * 4 + reg) * D_ + lr;
#pragma unroll
      for (int nb = 0; nb < 8; nb++)
        op[nb * 16] = (o[g][nb][reg] - mean) * rstd * gam[nb] + bet[nb];
    }
  }
}

extern "C" void kernel_launch(void* const* d_in, const int* in_sizes, int n_in,
                              void* d_out, int out_size, void* d_ws, size_t ws_size,
                              hipStream_t stream) {
  const float* q     = (const float*)d_in[0];
  const float* k     = (const float*)d_in[1];
  const float* v     = (const float*)d_in[2];
  const float* mask  = (const float*)d_in[3];
  const float* gamma = (const float*)d_in[4];
  const float* beta  = (const float*)d_in[5];
  float* out = (float*)d_out;

  unsigned short* khg = (unsigned short*)d_ws;
  unsigned int*   vtg = (unsigned int*)((char*)d_ws + VT_OFF);

  conv_kv<<<dim3(B_ * NTILE), dim3(256), 0, stream>>>(k, v, khg, vtg);
  attn_ln_mfma<<<dim3(256), dim3(256), 0, stream>>>(q, mask, gamma, beta,
                                                    khg, vtg, out);
}